// Round 8
// baseline (144.572 us; speedup 1.0000x reference)
//
#include <hip/hip_runtime.h>
#include <hip/hip_bf16.h>

#define IN_DIM  1024
#define OUT_DIM 1024
#define HID     4
#define BATCH   8192
#define NCOL    (OUT_DIM * HID)   // 4096 = GEMM M dimension (oh), N = 8192 (batch)

typedef __bf16 bf16x8 __attribute__((ext_vector_type(8)));
typedef float  f32x4  __attribute__((ext_vector_type(4)));

__device__ __forceinline__ unsigned short f2bf(float f) {
  union { float f; unsigned int u; } v; v.f = f;
  unsigned int u = v.u;
  u += 0x7FFFu + ((u >> 16) & 1u);   // round-to-nearest-even
  return (unsigned short)(u >> 16);
}

// ---- x: f32 [8192][1024] -> xg bf16 MFMA-B-fragment layout ----
// xg[c4][ko][bl][e]: c4 = batch>>4, ko = k>>3, bl = batch&15, e = k&7.
// One dwordx4 per lane = one 16x16x32 B-fragment; wave reads 1KB contiguous.
__global__ __launch_bounds__(256) void cvt_xg_kernel(const float* __restrict__ x,
                                                     uint4* __restrict__ xg) {
  int g = blockIdx.x * 256 + threadIdx.x;       // granule index (16B)
  int bl = g & 15, ko = (g >> 4) & 127, c4 = g >> 11;
  const float4* xp = (const float4*)(x + (size_t)(c4 * 16 + bl) * 1024 + ko * 8);
  float4 v0 = xp[0], v1 = xp[1];
  uint4 r;
  r.x = f2bf(v0.x) | ((unsigned)f2bf(v0.y) << 16);
  r.y = f2bf(v0.z) | ((unsigned)f2bf(v0.w) << 16);
  r.z = f2bf(v1.x) | ((unsigned)f2bf(v1.y) << 16);
  r.w = f2bf(v1.z) | ((unsigned)f2bf(v1.w) << 16);
  xg[g] = r;                                    // fully coalesced 16B/thread
}

// ---- W1: f32 (O,I,H) -> bf16 W1t[(o*4+h)][i]  (M x K row-major) ----
__global__ __launch_bounds__(256) void cvt_w1t_kernel(const float* __restrict__ W1,
                                                      ushort4* __restrict__ out) {
  int b = blockIdx.x;
  int g = ((b & 7) * ((int)gridDim.x >> 3) + (b >> 3)) * 256 + threadIdx.x;
  int i4 = g & 255;
  int oh = g >> 8;
  int h = oh & 3, o = oh >> 2;
  const float* src = W1 + (size_t)o * 4096 + h;
  ushort4 r;
  r.x = f2bf(src[(i4 * 4 + 0) * 4]);
  r.y = f2bf(src[(i4 * 4 + 1) * 4]);
  r.z = f2bf(src[(i4 * 4 + 2) * 4]);
  r.w = f2bf(src[(i4 * 4 + 3) * 4]);
  out[(size_t)oh * 256 + i4] = r;
}

__device__ __forceinline__ void gload16(const void* g, void* l) {
  __builtin_amdgcn_global_load_lds(
      (const __attribute__((address_space(1))) unsigned int*)g,
      (__attribute__((address_space(3))) unsigned int*)l, 16, 0, 0);
}

// ===== GEMM: C[oh][batch] = W1t x X^T; tile 256(M)x128(N), BK=64 ============
// 4 waves 2(M)x2(N), per-wave 128x64 = acc[8][4] f32x4 (16x16x32 MFMA).
// A via LDS (64 KiB dbuf, gload_lds); B direct from L2 (xg fragment layout).
// R8 deltas vs R7 (T4/T14): counted vmcnt(8) - never drain; B(kt+1) issued
// at kt START into ping-pong regs (full-kt latency cover); issue order
// stage(8,oldest) | sched_barrier | B(8) | sched_barrier pins the count.
// 4 MFMA clusters of 16 with their 4 ds_reads just before each, setprio'd.
__global__ __launch_bounds__(256, 2) void mlp_gemm_kernel(
    const unsigned short* __restrict__ A,   // w1t [4096][1024]  (M = oh)
    const unsigned short* __restrict__ Bg,  // xg fragment layout
    const f32x4* __restrict__ b1v,          // [1024] float4 per o
    const f32x4* __restrict__ w2v,          // [1024] float4 per o
    const float* __restrict__ b2,           // [1024]
    float* __restrict__ out) {              // [8192][1024]
  __shared__ __align__(16) unsigned short lds[32768];   // 64 KiB (A dbuf 2x32KB)

  const int bid = blockIdx.x;                     // 1024 blocks
  const int xcd = bid & 7, loc = bid >> 3;        // 128 blocks per XCD
  const int bn = xcd * 8 + (loc & 7);             // batch tile 0..63 (2MB/XCD L2 slice)
  const int bm = loc >> 3;                        // oh tile 0..15, bn-inner sweep
  const int tileM = bm * 256, tileN = bn * 128;

  const int t = threadIdx.x;
  const int lane = t & 63, wid = t >> 6;
  const int wm = wid >> 1, wn = wid & 1;          // wave -> (oh-half, batch-half)
  const int frow = lane & 15, jq = lane >> 4;

  // ---- A staging: thread t -> rows (t>>3)+32i, 16B slot t&7 (linear dest) ----
  const int sr8 = t >> 3, slt = t & 7;
  const int scol = ((slt ^ (sr8 & 7)) << 3);      // inverse-swizzled source col
  const unsigned short* Asrc = A + (size_t)(tileM + sr8) * IN_DIM + scol;

  auto stage = [&](int kt, int p) {               // 8 x gload16 = 32 KB
    const int kb = kt * 64;
    unsigned short* lA = lds + p * 16384 + t * 8;
#pragma unroll
    for (int i = 0; i < 8; ++i)
      gload16(Asrc + (size_t)(32 * i) * IN_DIM + kb, lA + i * 2048);
  };

  // ---- B fragment base: (c4, kt, ks, jq, frow) -> linear 16B granules ----
  const int c40 = (tileN >> 4) + wn * 4;
  const char* bpB = (const char*)Bg + (((size_t)c40 * 128 + jq) * 16 + frow) * 16;

  f32x4 acc[8][4];
#pragma unroll
  for (int m = 0; m < 8; ++m)
#pragma unroll
    for (int n = 0; n < 4; ++n) acc[m][n] = f32x4{0.f, 0.f, 0.f, 0.f};

  // A fragment read constants (R3-proven pattern, 262K confl measured)
  const int pk0 = (jq ^ (frow & 7)) << 3;         // ks0 swizzled slot (elems)
  const int aRow = (wm * 128 + frow) * 64;        // + mf*1024, + buf*16384

#define LOADB(dst, kt_) do {                                                   \
    _Pragma("unroll")                                                          \
    for (int nf_ = 0; nf_ < 4; ++nf_) {                                        \
      dst[nf_ * 2 + 0] = *(const bf16x8*)(bpB + nf_ * 32768 + (kt_) * 2048);   \
      dst[nf_ * 2 + 1] = *(const bf16x8*)(bpB + nf_ * 32768 + (kt_) * 2048 + 1024); \
    } } while (0)

  // one K-tile of compute: 4 clusters {4 ds_read -> 16 MFMA}, BF[nf*2+ks]
#define COMPUTE_KT(cur_, BF) do {                                              \
    const unsigned short* aB_ = lds + (cur_) * 16384 + aRow;                   \
    bf16x8 a_[4];                                                              \
    _Pragma("unroll")                                                          \
    for (int i_ = 0; i_ < 4; ++i_) a_[i_] = *(const bf16x8*)(aB_ + i_ * 1024 + pk0); \
    __builtin_amdgcn_s_setprio(1);                                             \
    _Pragma("unroll")                                                          \
    for (int mf_ = 0; mf_ < 4; ++mf_) {                                        \
      acc[mf_][0] = __builtin_amdgcn_mfma_f32_16x16x32_bf16(a_[mf_], BF[0], acc[mf_][0], 0, 0, 0); \
      acc[mf_][1] = __builtin_amdgcn_mfma_f32_16x16x32_bf16(a_[mf_], BF[2], acc[mf_][1], 0, 0, 0); \
      acc[mf_][2] = __builtin_amdgcn_mfma_f32_16x16x32_bf16(a_[mf_], BF[4], acc[mf_][2], 0, 0, 0); \
      acc[mf_][3] = __builtin_amdgcn_mfma_f32_16x16x32_bf16(a_[mf_], BF[6], acc[mf_][3], 0, 0, 0); \
    }                                                                          \
    __builtin_amdgcn_s_setprio(0);                                             \
    _Pragma("unroll")                                                          \
    for (int i_ = 0; i_ < 4; ++i_) a_[i_] = *(const bf16x8*)(aB_ + (4 + i_) * 1024 + pk0); \
    __builtin_amdgcn_s_setprio(1);                                             \
    _Pragma("unroll")                                                          \
    for (int mf_ = 0; mf_ < 4; ++mf_) {                                        \
      acc[4 + mf_][0] = __builtin_amdgcn_mfma_f32_16x16x32_bf16(a_[mf_], BF[0], acc[4 + mf_][0], 0, 0, 0); \
      acc[4 + mf_][1] = __builtin_amdgcn_mfma_f32_16x16x32_bf16(a_[mf_], BF[2], acc[4 + mf_][1], 0, 0, 0); \
      acc[4 + mf_][2] = __builtin_amdgcn_mfma_f32_16x16x32_bf16(a_[mf_], BF[4], acc[4 + mf_][2], 0, 0, 0); \
      acc[4 + mf_][3] = __builtin_amdgcn_mfma_f32_16x16x32_bf16(a_[mf_], BF[6], acc[4 + mf_][3], 0, 0, 0); \
    }                                                                          \
    __builtin_amdgcn_s_setprio(0);                                             \
    _Pragma("unroll")                                                          \
    for (int i_ = 0; i_ < 4; ++i_) a_[i_] = *(const bf16x8*)(aB_ + i_ * 1024 + (pk0 ^ 32)); \
    __builtin_amdgcn_s_setprio(1);                                             \
    _Pragma("unroll")                                                          \
    for (int mf_ = 0; mf_ < 4; ++mf_) {                                        \
      acc[mf_][0] = __builtin_amdgcn_mfma_f32_16x16x32_bf16(a_[mf_], BF[1], acc[mf_][0], 0, 0, 0); \
      acc[mf_][1] = __builtin_amdgcn_mfma_f32_16x16x32_bf16(a_[mf_], BF[3], acc[mf_][1], 0, 0, 0); \
      acc[mf_][2] = __builtin_amdgcn_mfma_f32_16x16x32_bf16(a_[mf_], BF[5], acc[mf_][2], 0, 0, 0); \
      acc[mf_][3] = __builtin_amdgcn_mfma_f32_16x16x32_bf16(a_[mf_], BF[7], acc[mf_][3], 0, 0, 0); \
    }                                                                          \
    __builtin_amdgcn_s_setprio(0);                                             \
    _Pragma("unroll")                                                          \
    for (int i_ = 0; i_ < 4; ++i_) a_[i_] = *(const bf16x8*)(aB_ + (4 + i_) * 1024 + (pk0 ^ 32)); \
    __builtin_amdgcn_s_setprio(1);                                             \
    _Pragma("unroll")                                                          \
    for (int mf_ = 0; mf_ < 4; ++mf_) {                                        \
      acc[4 + mf_][0] = __builtin_amdgcn_mfma_f32_16x16x32_bf16(a_[mf_], BF[1], acc[4 + mf_][0], 0, 0, 0); \
      acc[4 + mf_][1] = __builtin_amdgcn_mfma_f32_16x16x32_bf16(a_[mf_], BF[3], acc[4 + mf_][1], 0, 0, 0); \
      acc[4 + mf_][2] = __builtin_amdgcn_mfma_f32_16x16x32_bf16(a_[mf_], BF[5], acc[4 + mf_][2], 0, 0, 0); \
      acc[4 + mf_][3] = __builtin_amdgcn_mfma_f32_16x16x32_bf16(a_[mf_], BF[7], acc[4 + mf_][3], 0, 0, 0); \
    }                                                                          \
    __builtin_amdgcn_s_setprio(0);                                             \
  } while (0)

  bf16x8 bA[8], bB[8];

  // prologue: stage(0) [oldest 8] | B(0) [8] ; vmcnt(8) => stage(0) done
  stage(0, 0);
  __builtin_amdgcn_sched_barrier(0);
  LOADB(bA, 0);
  __builtin_amdgcn_sched_barrier(0);
  asm volatile("s_waitcnt vmcnt(8)" ::: "memory");
  __builtin_amdgcn_s_barrier();

#pragma unroll 1
  for (int g = 0; g < 16; g += 2) {
    // ---- kt = g (even): buf 0, consume bA, fill bB ----
    {
      if (g < 15) {
        stage(g + 1, 1);
        __builtin_amdgcn_sched_barrier(0);
        LOADB(bB, g + 1);
        __builtin_amdgcn_sched_barrier(0);
      }
      COMPUTE_KT(0, bA);
      if (g < 15) asm volatile("s_waitcnt vmcnt(8)" ::: "memory");
      __builtin_amdgcn_s_barrier();
    }
    // ---- kt = g+1 (odd): buf 1, consume bB, fill bA ----
    {
      if (g + 1 < 15) {
        stage(g + 2, 0);
        __builtin_amdgcn_sched_barrier(0);
        LOADB(bA, g + 2);
        __builtin_amdgcn_sched_barrier(0);
      }
      COMPUTE_KT(1, bB);
      if (g + 1 < 15) asm volatile("s_waitcnt vmcnt(8)" ::: "memory");
      __builtin_amdgcn_s_barrier();
    }
  }
  __syncthreads();   // fence before LDS reuse

  // ---- fused epilogue: in-register hidden-dot ----
  // C/D 16x16: col = frow = batch_local, row16 = jq*4 + j -> h = j,
  // o_loc = wm*32 + mf*4 + jq.
  float* LE = (float*)lds;                        // [128 batch][65] f32 = 33.3 KB
  const int obase = tileM >> 2;                   // block's 64 o-values
#pragma unroll
  for (int mf = 0; mf < 8; ++mf) {
    int o_loc = wm * 32 + mf * 4 + jq;
    f32x4 b1q = b1v[obase + o_loc];
    f32x4 w2q = w2v[obase + o_loc];
#pragma unroll
    for (int nf = 0; nf < 4; ++nf) {
      int bat = wn * 64 + nf * 16 + frow;
      float v = 0.f;
#pragma unroll
      for (int h = 0; h < 4; ++h) {
        float hj = acc[mf][nf][h] + b1q[h];
        hj = (hj >= 0.f) ? hj : 0.1f * hj;        // LeakyReLU(0.1)
        v += hj * w2q[h];
      }
      LE[bat * 65 + o_loc] = v;                   // bank=(bat+o_loc)%32: 2-way
    }
  }
  __syncthreads();

  // coalesced store: out[tileN..+128)[obase..+64)
  const int col = t & 63, rowb = t >> 6;
  const float b2s = b2[obase + col];
  float* outB = out + (size_t)tileN * OUT_DIM + obase;
#pragma unroll
  for (int i = 0; i < 32; ++i) {
    int row = rowb + i * 4;
    outB[(size_t)row * OUT_DIM + col] = LE[row * 65 + col] + b2s;
  }
#undef LOADB
#undef COMPUTE_KT
}

// ---- safety fallback (pure f32, used only if d_ws is too small) ----
__global__ __launch_bounds__(256) void fallback_kernel(
    const float* __restrict__ x, const float* __restrict__ W1,
    const float* __restrict__ b1, const float* __restrict__ W2,
    const float* __restrict__ b2, float* __restrict__ out) {
  int idx = blockIdx.x * 256 + threadIdx.x;
  if (idx >= BATCH * OUT_DIM) return;
  int bb = idx >> 10, o = idx & 1023;
  const float4* w1p = (const float4*)(W1 + (size_t)o * 4096);
  const float*  xp  = x + (size_t)bb * 1024;
  float4 acc = *(const float4*)(b1 + o * 4);
  for (int i = 0; i < 1024; ++i) {
    float xv = xp[i];
    float4 w = w1p[i];
    acc.x += xv * w.x; acc.y += xv * w.y; acc.z += xv * w.z; acc.w += xv * w.w;
  }
  float4 w2 = *(const float4*)(W2 + o * 4);
  float r = b2[o];
  r += ((acc.x >= 0.f) ? acc.x : 0.1f * acc.x) * w2.x;
  r += ((acc.y >= 0.f) ? acc.y : 0.1f * acc.y) * w2.y;
  r += ((acc.z >= 0.f) ? acc.z : 0.1f * acc.z) * w2.z;
  r += ((acc.w >= 0.f) ? acc.w : 0.1f * acc.w) * w2.w;
  out[(size_t)bb * OUT_DIM + o] = r;
}

extern "C" void kernel_launch(void* const* d_in, const int* in_sizes, int n_in,
                              void* d_out, int out_size, void* d_ws, size_t ws_size,
                              hipStream_t stream) {
  const float* x  = (const float*)d_in[0];
  const float* W1 = (const float*)d_in[1];
  const float* b1 = (const float*)d_in[2];
  const float* W2 = (const float*)d_in[3];
  const float* b2 = (const float*)d_in[4];
  float* out = (float*)d_out;

  size_t need = (size_t)BATCH * IN_DIM * 2 + (size_t)NCOL * IN_DIM * 2;  // 25.2 MB
  if (ws_size >= need) {
    unsigned short* xg  = (unsigned short*)d_ws;
    unsigned short* w1t = xg + (size_t)BATCH * IN_DIM;
    cvt_xg_kernel<<<(BATCH * IN_DIM / 8) / 256, 256, 0, stream>>>(x, (uint4*)xg);
    cvt_w1t_kernel<<<(NCOL * IN_DIM / 4) / 256, 256, 0, stream>>>(W1, (ushort4*)w1t);
    mlp_gemm_kernel<<<(NCOL / 256) * (BATCH / 128), 256, 0, stream>>>(
        w1t, xg, (const f32x4*)b1, (const f32x4*)W2, b2, out);
  } else {
    fallback_kernel<<<(BATCH * OUT_DIM + 255) / 256, 256, 0, stream>>>(x, W1, b1, W2, b2, out);
  }
}

// Round 9
// 84.795 us; speedup vs baseline: 1.7050x; 1.7050x over previous
//
#include <hip/hip_runtime.h>
#include <hip/hip_bf16.h>

#define IN_DIM  1024
#define OUT_DIM 1024
#define HID     4
#define BATCH   8192
#define NCOL    (OUT_DIM * HID)   // 4096 = GEMM M dimension (oh), N = 8192 (batch)

typedef __bf16 bf16x8 __attribute__((ext_vector_type(8)));
typedef float  f32x4  __attribute__((ext_vector_type(4)));

__device__ __forceinline__ unsigned short f2bf(float f) {
  union { float f; unsigned int u; } v; v.f = f;
  unsigned int u = v.u;
  u += 0x7FFFu + ((u >> 16) & 1u);   // round-to-nearest-even
  return (unsigned short)(u >> 16);
}

// ---- x: f32 [8192][1024] -> xg bf16 MFMA-B-fragment layout ----
// xg[c4][ko][bl][e]: c4 = batch>>4, ko = k>>3, bl = batch&15, e = k&7.
// One dwordx4 per lane = one 16x16x32 B-fragment; wave reads 1KB contiguous.
__global__ __launch_bounds__(256) void cvt_xg_kernel(const float* __restrict__ x,
                                                     uint4* __restrict__ xg) {
  int g = blockIdx.x * 256 + threadIdx.x;       // granule index (16B)
  int bl = g & 15, ko = (g >> 4) & 127, c4 = g >> 11;
  const float4* xp = (const float4*)(x + (size_t)(c4 * 16 + bl) * 1024 + ko * 8);
  float4 v0 = xp[0], v1 = xp[1];
  uint4 r;
  r.x = f2bf(v0.x) | ((unsigned)f2bf(v0.y) << 16);
  r.y = f2bf(v0.z) | ((unsigned)f2bf(v0.w) << 16);
  r.z = f2bf(v1.x) | ((unsigned)f2bf(v1.y) << 16);
  r.w = f2bf(v1.z) | ((unsigned)f2bf(v1.w) << 16);
  xg[g] = r;                                    // fully coalesced 16B/thread
}

// ---- W1: f32 (O,I,H) -> bf16 W1t[(o*4+h)][i]  (M x K row-major) ----
__global__ __launch_bounds__(256) void cvt_w1t_kernel(const float* __restrict__ W1,
                                                      ushort4* __restrict__ out) {
  int b = blockIdx.x;
  int g = ((b & 7) * ((int)gridDim.x >> 3) + (b >> 3)) * 256 + threadIdx.x;
  int i4 = g & 255;
  int oh = g >> 8;
  int h = oh & 3, o = oh >> 2;
  const float* src = W1 + (size_t)o * 4096 + h;
  ushort4 r;
  r.x = f2bf(src[(i4 * 4 + 0) * 4]);
  r.y = f2bf(src[(i4 * 4 + 1) * 4]);
  r.z = f2bf(src[(i4 * 4 + 2) * 4]);
  r.w = f2bf(src[(i4 * 4 + 3) * 4]);
  out[(size_t)oh * 256 + i4] = r;
}

__device__ __forceinline__ void gload16(const void* g, void* l) {
  __builtin_amdgcn_global_load_lds(
      (const __attribute__((address_space(1))) unsigned int*)g,
      (__attribute__((address_space(3))) unsigned int*)l, 16, 0, 0);
}

// ===== GEMM: C[oh][batch] = W1t x X^T; tile 128(M)x128(N), BK=64 ============
// 4 waves, grid 1(M)x4(N): per-wave 128x32 = acc[8][2] f32x4 (64 AGPR only).
// A via LDS (32 KiB dbuf, gload_lds, proven swizzle/read pattern); B direct
// from L2 (xg fragment layout, no wn duplication -> min L2 traffic).
// R9 vs R7: occupancy 2 -> 3 blocks/CU (3 waves/SIMD) by shrinking acc+LDS;
// that TLP is what hides ds_read/lgkm/barrier latency (R8's manual schedule
// proved scheduling wasn't the lever).
__global__ __launch_bounds__(256, 3) void mlp_gemm_kernel(
    const unsigned short* __restrict__ A,   // w1t [4096][1024]  (M = oh)
    const unsigned short* __restrict__ Bg,  // xg fragment layout
    const f32x4* __restrict__ b1v,          // [1024] float4 per o
    const f32x4* __restrict__ w2v,          // [1024] float4 per o
    const float* __restrict__ b2,           // [1024]
    float* __restrict__ out) {              // [8192][1024]
  __shared__ __align__(16) unsigned short lds[16384];   // 32 KiB (A dbuf 2x16KB)

  const int bid = blockIdx.x;                     // 2048 blocks
  const int xcd = bid & 7, loc = bid >> 3;        // 256 blocks per XCD
  const int bn = xcd * 8 + (loc & 7);             // batch tile 0..63 (2MB/XCD L2 slice)
  const int bm = loc >> 3;                        // oh tile 0..31, bn-inner sweep
  const int tileM = bm * 128, tileN = bn * 128;

  const int t = threadIdx.x;
  const int lane = t & 63, wn = t >> 6;           // wave -> batch quarter
  const int frow = lane & 15, jq = lane >> 4;

  // ---- A staging: thread t -> rows (t>>3)+32i (i<4), 16B slot t&7 ----
  const int sr8 = t >> 3, slt = t & 7;
  const int scol = ((slt ^ (sr8 & 7)) << 3);      // inverse-swizzled source col
  const unsigned short* Asrc = A + (size_t)(tileM + sr8) * IN_DIM + scol;

  auto stage = [&](int kt, int p) {               // 4 x gload16 = 16 KB
    const int kb = kt * 64;
    unsigned short* lA = lds + p * 8192 + t * 8;
#pragma unroll
    for (int i = 0; i < 4; ++i)
      gload16(Asrc + (size_t)(32 * i) * IN_DIM + kb, lA + i * 2048);
  };

  // ---- B fragment base: c4 = tileN/16 + wn*2 (+nf); ko = kt*8+ks*4+jq ----
  const int c40 = (tileN >> 4) + wn * 2;
  const char* bpB = (const char*)Bg + (((size_t)c40 * 128 + jq) * 16 + frow) * 16;

  f32x4 acc[8][2];
#pragma unroll
  for (int m = 0; m < 8; ++m) {
    acc[m][0] = f32x4{0.f, 0.f, 0.f, 0.f};
    acc[m][1] = f32x4{0.f, 0.f, 0.f, 0.f};
  }

  // A fragment read constants (proven pattern: frow rows, jq slots)
  const int pk0 = (jq ^ (frow & 7)) << 3;         // ks0 swizzled slot (elems)
  const int pk1 = pk0 ^ 32;                       // ks1

  stage(0, 0);
  asm volatile("s_waitcnt vmcnt(0)" ::: "memory");
  __builtin_amdgcn_s_barrier();

  for (int kt = 0; kt < 16; ++kt) {
    const int cur = kt & 1;
    if (kt < 15) stage(kt + 1, cur ^ 1);

    const char* bk = bpB + kt * 2048;
    bf16x8 b00 = *(const bf16x8*)(bk);                  // nf0 ks0
    bf16x8 b01 = *(const bf16x8*)(bk + 1024);           // nf0 ks1
    bf16x8 b10 = *(const bf16x8*)(bk + 32768);          // nf1 ks0
    bf16x8 b11 = *(const bf16x8*)(bk + 32768 + 1024);   // nf1 ks1

    const unsigned short* aB = lds + cur * 8192 + frow * 64;
    bf16x8 a[4];
    // ks0, mf 0..3
#pragma unroll
    for (int i = 0; i < 4; ++i) a[i] = *(const bf16x8*)(aB + i * 1024 + pk0);
#pragma unroll
    for (int mf = 0; mf < 4; ++mf) {
      acc[mf][0] = __builtin_amdgcn_mfma_f32_16x16x32_bf16(a[mf], b00, acc[mf][0], 0, 0, 0);
      acc[mf][1] = __builtin_amdgcn_mfma_f32_16x16x32_bf16(a[mf], b10, acc[mf][1], 0, 0, 0);
    }
    // ks0, mf 4..7
#pragma unroll
    for (int i = 0; i < 4; ++i) a[i] = *(const bf16x8*)(aB + (4 + i) * 1024 + pk0);
#pragma unroll
    for (int mf = 0; mf < 4; ++mf) {
      acc[4 + mf][0] = __builtin_amdgcn_mfma_f32_16x16x32_bf16(a[mf], b00, acc[4 + mf][0], 0, 0, 0);
      acc[4 + mf][1] = __builtin_amdgcn_mfma_f32_16x16x32_bf16(a[mf], b10, acc[4 + mf][1], 0, 0, 0);
    }
    // ks1, mf 0..3
#pragma unroll
    for (int i = 0; i < 4; ++i) a[i] = *(const bf16x8*)(aB + i * 1024 + pk1);
#pragma unroll
    for (int mf = 0; mf < 4; ++mf) {
      acc[mf][0] = __builtin_amdgcn_mfma_f32_16x16x32_bf16(a[mf], b01, acc[mf][0], 0, 0, 0);
      acc[mf][1] = __builtin_amdgcn_mfma_f32_16x16x32_bf16(a[mf], b11, acc[mf][1], 0, 0, 0);
    }
    // ks1, mf 4..7
#pragma unroll
    for (int i = 0; i < 4; ++i) a[i] = *(const bf16x8*)(aB + (4 + i) * 1024 + pk1);
#pragma unroll
    for (int mf = 0; mf < 4; ++mf) {
      acc[4 + mf][0] = __builtin_amdgcn_mfma_f32_16x16x32_bf16(a[mf], b01, acc[4 + mf][0], 0, 0, 0);
      acc[4 + mf][1] = __builtin_amdgcn_mfma_f32_16x16x32_bf16(a[mf], b11, acc[4 + mf][1], 0, 0, 0);
    }

    if (kt < 15) {
      asm volatile("s_waitcnt vmcnt(0)" ::: "memory");  // stage(kt+1) landed
      __builtin_amdgcn_s_barrier();
    }
  }
  __syncthreads();   // all frag reads done -> safe to reuse LDS

  // ---- fused epilogue: in-register hidden-dot ----
  // C/D 16x16: col = frow = batch_local, row16 = jq*4 + j -> h = j,
  // o_loc = mf*4 + jq (block's 32 o-values).
  float* LE = (float*)lds;                        // [128 batch][33] f32 = 16.9 KB
  const int obase = tileM >> 2;
#pragma unroll
  for (int mf = 0; mf < 8; ++mf) {
    int o_loc = mf * 4 + jq;
    f32x4 b1q = b1v[obase + o_loc];
    f32x4 w2q = w2v[obase + o_loc];
#pragma unroll
    for (int nf = 0; nf < 2; ++nf) {
      int bat = wn * 32 + nf * 16 + frow;
      float v = 0.f;
#pragma unroll
      for (int h = 0; h < 4; ++h) {
        float hj = acc[mf][nf][h] + b1q[h];
        hj = (hj >= 0.f) ? hj : 0.1f * hj;        // LeakyReLU(0.1)
        v += hj * w2q[h];
      }
      LE[bat * 33 + o_loc] = v;                   // stride 33: ~2-way banks
    }
  }
  __syncthreads();

  // coalesced store: out[tileN..+128)[obase..+32)
  const int col = t & 31, rowb = t >> 5;
  const float b2s = b2[obase + col];
  float* outB = out + (size_t)tileN * OUT_DIM + obase;
#pragma unroll
  for (int i = 0; i < 16; ++i) {
    int row = rowb + i * 8;
    outB[(size_t)row * OUT_DIM + col] = LE[row * 33 + col] + b2s;
  }
}

// ---- safety fallback (pure f32, used only if d_ws is too small) ----
__global__ __launch_bounds__(256) void fallback_kernel(
    const float* __restrict__ x, const float* __restrict__ W1,
    const float* __restrict__ b1, const float* __restrict__ W2,
    const float* __restrict__ b2, float* __restrict__ out) {
  int idx = blockIdx.x * 256 + threadIdx.x;
  if (idx >= BATCH * OUT_DIM) return;
  int bb = idx >> 10, o = idx & 1023;
  const float4* w1p = (const float4*)(W1 + (size_t)o * 4096);
  const float*  xp  = x + (size_t)bb * 1024;
  float4 acc = *(const float4*)(b1 + o * 4);
  for (int i = 0; i < 1024; ++i) {
    float xv = xp[i];
    float4 w = w1p[i];
    acc.x += xv * w.x; acc.y += xv * w.y; acc.z += xv * w.z; acc.w += xv * w.w;
  }
  float4 w2 = *(const float4*)(W2 + o * 4);
  float r = b2[o];
  r += ((acc.x >= 0.f) ? acc.x : 0.1f * acc.x) * w2.x;
  r += ((acc.y >= 0.f) ? acc.y : 0.1f * acc.y) * w2.y;
  r += ((acc.z >= 0.f) ? acc.z : 0.1f * acc.z) * w2.z;
  r += ((acc.w >= 0.f) ? acc.w : 0.1f * acc.w) * w2.w;
  out[(size_t)bb * OUT_DIM + o] = r;
}

extern "C" void kernel_launch(void* const* d_in, const int* in_sizes, int n_in,
                              void* d_out, int out_size, void* d_ws, size_t ws_size,
                              hipStream_t stream) {
  const float* x  = (const float*)d_in[0];
  const float* W1 = (const float*)d_in[1];
  const float* b1 = (const float*)d_in[2];
  const float* W2 = (const float*)d_in[3];
  const float* b2 = (const float*)d_in[4];
  float* out = (float*)d_out;

  size_t need = (size_t)BATCH * IN_DIM * 2 + (size_t)NCOL * IN_DIM * 2;  // 25.2 MB
  if (ws_size >= need) {
    unsigned short* xg  = (unsigned short*)d_ws;
    unsigned short* w1t = xg + (size_t)BATCH * IN_DIM;
    cvt_xg_kernel<<<(BATCH * IN_DIM / 8) / 256, 256, 0, stream>>>(x, (uint4*)xg);
    cvt_w1t_kernel<<<(NCOL * IN_DIM / 4) / 256, 256, 0, stream>>>(W1, (ushort4*)w1t);
    mlp_gemm_kernel<<<(NCOL / 128) * (BATCH / 128), 256, 0, stream>>>(
        w1t, xg, (const f32x4*)b1, (const f32x4*)W2, b2, out);
  } else {
    fallback_kernel<<<(BATCH * OUT_DIM + 255) / 256, 256, 0, stream>>>(x, W1, b1, W2, b2, out);
  }
}

// Round 10
// 81.846 us; speedup vs baseline: 1.7664x; 1.0360x over previous
//
#include <hip/hip_runtime.h>
#include <hip/hip_bf16.h>

#define IN_DIM  1024
#define OUT_DIM 1024
#define HID     4
#define BATCH   8192
#define NCOL    (OUT_DIM * HID)   // 4096 = GEMM M dimension (oh), N = 8192 (batch)

typedef __bf16 bf16x8 __attribute__((ext_vector_type(8)));
typedef float  f32x4  __attribute__((ext_vector_type(4)));

__device__ __forceinline__ unsigned short f2bf(float f) {
  union { float f; unsigned int u; } v; v.f = f;
  unsigned int u = v.u;
  u += 0x7FFFu + ((u >> 16) & 1u);   // round-to-nearest-even
  return (unsigned short)(u >> 16);
}

// ---- merged conversion pre-pass (single launch) ----
// blocks [0,4096): x f32 [8192][1024] -> xg bf16 MFMA-B-fragment layout
//   xg[c4][ko][bl][e]: c4 = batch>>4, ko = k>>3, bl = batch&15, e = k&7.
//   One dwordx4 per lane = one 16x16x32 B-fragment (1KB contiguous per wave).
// blocks [4096,8192): W1 f32 (O,I,H) -> bf16 W1t[(o*4+h)][i] (M x K row-major)
__global__ __launch_bounds__(256) void cvt_all_kernel(const float* __restrict__ x,
                                                      uint4* __restrict__ xg,
                                                      const float* __restrict__ W1,
                                                      ushort4* __restrict__ w1t) {
  int blk = blockIdx.x;
  if (blk < 4096) {
    int g = blk * 256 + threadIdx.x;            // granule index (16B)
    int bl = g & 15, ko = (g >> 4) & 127, c4 = g >> 11;
    const float4* xp = (const float4*)(x + (size_t)(c4 * 16 + bl) * 1024 + ko * 8);
    float4 v0 = xp[0], v1 = xp[1];
    uint4 r;
    r.x = f2bf(v0.x) | ((unsigned)f2bf(v0.y) << 16);
    r.y = f2bf(v0.z) | ((unsigned)f2bf(v0.w) << 16);
    r.z = f2bf(v1.x) | ((unsigned)f2bf(v1.y) << 16);
    r.w = f2bf(v1.z) | ((unsigned)f2bf(v1.w) << 16);
    xg[g] = r;                                  // fully coalesced 16B/thread
  } else {
    int b = blk - 4096;
    int g = ((b & 7) * 512 + (b >> 3)) * 256 + threadIdx.x;  // XCD-grouped
    int i4 = g & 255;
    int oh = g >> 8;
    int h = oh & 3, o = oh >> 2;
    const float* src = W1 + (size_t)o * 4096 + h;
    ushort4 r;
    r.x = f2bf(src[(i4 * 4 + 0) * 4]);
    r.y = f2bf(src[(i4 * 4 + 1) * 4]);
    r.z = f2bf(src[(i4 * 4 + 2) * 4]);
    r.w = f2bf(src[(i4 * 4 + 3) * 4]);
    w1t[(size_t)oh * 256 + i4] = r;
  }
}

__device__ __forceinline__ void gload16(const void* g, void* l) {
  __builtin_amdgcn_global_load_lds(
      (const __attribute__((address_space(1))) unsigned int*)g,
      (__attribute__((address_space(3))) unsigned int*)l, 16, 0, 0);
}

// ===== GEMM: C[oh][batch] = W1t x X^T; tile 128(M)x128(N), BK=64 ============
// 4 waves, grid 1(M)x4(N): per-wave 128x32 = acc[8][2] f32x4 (64 AGPR only).
// A via LDS (32 KiB dbuf, gload_lds, proven swizzle/read pattern); B direct
// from L2 (xg fragment layout, no wn duplication -> min L2 traffic).
// R10 vs R9: __launch_bounds__(256,4) -> 4 blocks/CU (16 waves/CU). Register
// budget is exactly 64 VGPR + 64 AGPR = 128/wave, the 4-waves/SIMD limit.
__global__ __launch_bounds__(256, 4) void mlp_gemm_kernel(
    const unsigned short* __restrict__ A,   // w1t [4096][1024]  (M = oh)
    const unsigned short* __restrict__ Bg,  // xg fragment layout
    const f32x4* __restrict__ b1v,          // [1024] float4 per o
    const f32x4* __restrict__ w2v,          // [1024] float4 per o
    const float* __restrict__ b2,           // [1024]
    float* __restrict__ out) {              // [8192][1024]
  __shared__ __align__(16) unsigned short lds[16384];   // 32 KiB (A dbuf 2x16KB)

  const int bid = blockIdx.x;                     // 2048 blocks
  const int xcd = bid & 7, loc = bid >> 3;        // 256 blocks per XCD
  const int bn = xcd * 8 + (loc & 7);             // batch tile 0..63 (2MB/XCD L2 slice)
  const int bm = loc >> 3;                        // oh tile 0..31, bn-inner sweep
  const int tileM = bm * 128, tileN = bn * 128;

  const int t = threadIdx.x;
  const int lane = t & 63, wn = t >> 6;           // wave -> batch quarter
  const int frow = lane & 15, jq = lane >> 4;

  // ---- A staging: thread t -> rows (t>>3)+32i (i<4), 16B slot t&7 ----
  const int sr8 = t >> 3, slt = t & 7;
  const int scol = ((slt ^ (sr8 & 7)) << 3);      // inverse-swizzled source col
  const unsigned short* Asrc = A + (size_t)(tileM + sr8) * IN_DIM + scol;

  auto stage = [&](int kt, int p) {               // 4 x gload16 = 16 KB
    const int kb = kt * 64;
    unsigned short* lA = lds + p * 8192 + t * 8;
#pragma unroll
    for (int i = 0; i < 4; ++i)
      gload16(Asrc + (size_t)(32 * i) * IN_DIM + kb, lA + i * 2048);
  };

  // ---- B fragment base: c4 = tileN/16 + wn*2 (+nf); ko = kt*8+ks*4+jq ----
  const int c40 = (tileN >> 4) + wn * 2;
  const char* bpB = (const char*)Bg + (((size_t)c40 * 128 + jq) * 16 + frow) * 16;

  f32x4 acc[8][2];
#pragma unroll
  for (int m = 0; m < 8; ++m) {
    acc[m][0] = f32x4{0.f, 0.f, 0.f, 0.f};
    acc[m][1] = f32x4{0.f, 0.f, 0.f, 0.f};
  }

  // A fragment read constants (proven pattern: frow rows, jq slots)
  const int pk0 = (jq ^ (frow & 7)) << 3;         // ks0 swizzled slot (elems)
  const int pk1 = pk0 ^ 32;                       // ks1

  stage(0, 0);
  asm volatile("s_waitcnt vmcnt(0)" ::: "memory");
  __builtin_amdgcn_s_barrier();

  for (int kt = 0; kt < 16; ++kt) {
    const int cur = kt & 1;
    if (kt < 15) stage(kt + 1, cur ^ 1);

    const char* bk = bpB + kt * 2048;
    bf16x8 b00 = *(const bf16x8*)(bk);                  // nf0 ks0
    bf16x8 b01 = *(const bf16x8*)(bk + 1024);           // nf0 ks1
    bf16x8 b10 = *(const bf16x8*)(bk + 32768);          // nf1 ks0
    bf16x8 b11 = *(const bf16x8*)(bk + 32768 + 1024);   // nf1 ks1

    const unsigned short* aB = lds + cur * 8192 + frow * 64;
    bf16x8 a[4];
    // ks0, mf 0..3
#pragma unroll
    for (int i = 0; i < 4; ++i) a[i] = *(const bf16x8*)(aB + i * 1024 + pk0);
#pragma unroll
    for (int mf = 0; mf < 4; ++mf) {
      acc[mf][0] = __builtin_amdgcn_mfma_f32_16x16x32_bf16(a[mf], b00, acc[mf][0], 0, 0, 0);
      acc[mf][1] = __builtin_amdgcn_mfma_f32_16x16x32_bf16(a[mf], b10, acc[mf][1], 0, 0, 0);
    }
    // ks0, mf 4..7
#pragma unroll
    for (int i = 0; i < 4; ++i) a[i] = *(const bf16x8*)(aB + (4 + i) * 1024 + pk0);
#pragma unroll
    for (int mf = 0; mf < 4; ++mf) {
      acc[4 + mf][0] = __builtin_amdgcn_mfma_f32_16x16x32_bf16(a[mf], b00, acc[4 + mf][0], 0, 0, 0);
      acc[4 + mf][1] = __builtin_amdgcn_mfma_f32_16x16x32_bf16(a[mf], b10, acc[4 + mf][1], 0, 0, 0);
    }
    // ks1, mf 0..3
#pragma unroll
    for (int i = 0; i < 4; ++i) a[i] = *(const bf16x8*)(aB + i * 1024 + pk1);
#pragma unroll
    for (int mf = 0; mf < 4; ++mf) {
      acc[mf][0] = __builtin_amdgcn_mfma_f32_16x16x32_bf16(a[mf], b01, acc[mf][0], 0, 0, 0);
      acc[mf][1] = __builtin_amdgcn_mfma_f32_16x16x32_bf16(a[mf], b11, acc[mf][1], 0, 0, 0);
    }
    // ks1, mf 4..7
#pragma unroll
    for (int i = 0; i < 4; ++i) a[i] = *(const bf16x8*)(aB + (4 + i) * 1024 + pk1);
#pragma unroll
    for (int mf = 0; mf < 4; ++mf) {
      acc[4 + mf][0] = __builtin_amdgcn_mfma_f32_16x16x32_bf16(a[mf], b01, acc[4 + mf][0], 0, 0, 0);
      acc[4 + mf][1] = __builtin_amdgcn_mfma_f32_16x16x32_bf16(a[mf], b11, acc[4 + mf][1], 0, 0, 0);
    }

    if (kt < 15) {
      asm volatile("s_waitcnt vmcnt(0)" ::: "memory");  // stage(kt+1) landed
      __builtin_amdgcn_s_barrier();
    }
  }
  __syncthreads();   // all frag reads done -> safe to reuse LDS

  // ---- fused epilogue: in-register hidden-dot ----
  // C/D 16x16: col = frow = batch_local, row16 = jq*4 + j -> h = j,
  // o_loc = mf*4 + jq (block's 32 o-values).
  float* LE = (float*)lds;                        // [128 batch][33] f32 = 16.9 KB
  const int obase = tileM >> 2;
#pragma unroll
  for (int mf = 0; mf < 8; ++mf) {
    int o_loc = mf * 4 + jq;
    f32x4 b1q = b1v[obase + o_loc];
    f32x4 w2q = w2v[obase + o_loc];
#pragma unroll
    for (int nf = 0; nf < 2; ++nf) {
      int bat = wn * 32 + nf * 16 + frow;
      float v = 0.f;
#pragma unroll
      for (int h = 0; h < 4; ++h) {
        float hj = acc[mf][nf][h] + b1q[h];
        hj = (hj >= 0.f) ? hj : 0.1f * hj;        // LeakyReLU(0.1)
        v += hj * w2q[h];
      }
      LE[bat * 33 + o_loc] = v;                   // stride 33: ~2-way banks
    }
  }
  __syncthreads();

  // coalesced store: out[tileN..+128)[obase..+32)
  const int col = t & 31, rowb = t >> 5;
  const float b2s = b2[obase + col];
  float* outB = out + (size_t)tileN * OUT_DIM + obase;
#pragma unroll
  for (int i = 0; i < 16; ++i) {
    int row = rowb + i * 8;
    outB[(size_t)row * OUT_DIM + col] = LE[row * 33 + col] + b2s;
  }
}

// ---- safety fallback (pure f32, used only if d_ws is too small) ----
__global__ __launch_bounds__(256) void fallback_kernel(
    const float* __restrict__ x, const float* __restrict__ W1,
    const float* __restrict__ b1, const float* __restrict__ W2,
    const float* __restrict__ b2, float* __restrict__ out) {
  int idx = blockIdx.x * 256 + threadIdx.x;
  if (idx >= BATCH * OUT_DIM) return;
  int bb = idx >> 10, o = idx & 1023;
  const float4* w1p = (const float4*)(W1 + (size_t)o * 4096);
  const float*  xp  = x + (size_t)bb * 1024;
  float4 acc = *(const float4*)(b1 + o * 4);
  for (int i = 0; i < 1024; ++i) {
    float xv = xp[i];
    float4 w = w1p[i];
    acc.x += xv * w.x; acc.y += xv * w.y; acc.z += xv * w.z; acc.w += xv * w.w;
  }
  float4 w2 = *(const float4*)(W2 + o * 4);
  float r = b2[o];
  r += ((acc.x >= 0.f) ? acc.x : 0.1f * acc.x) * w2.x;
  r += ((acc.y >= 0.f) ? acc.y : 0.1f * acc.y) * w2.y;
  r += ((acc.z >= 0.f) ? acc.z : 0.1f * acc.z) * w2.z;
  r += ((acc.w >= 0.f) ? acc.w : 0.1f * acc.w) * w2.w;
  out[(size_t)bb * OUT_DIM + o] = r;
}

extern "C" void kernel_launch(void* const* d_in, const int* in_sizes, int n_in,
                              void* d_out, int out_size, void* d_ws, size_t ws_size,
                              hipStream_t stream) {
  const float* x  = (const float*)d_in[0];
  const float* W1 = (const float*)d_in[1];
  const float* b1 = (const float*)d_in[2];
  const float* W2 = (const float*)d_in[3];
  const float* b2 = (const float*)d_in[4];
  float* out = (float*)d_out;

  size_t need = (size_t)BATCH * IN_DIM * 2 + (size_t)NCOL * IN_DIM * 2;  // 25.2 MB
  if (ws_size >= need) {
    unsigned short* xg  = (unsigned short*)d_ws;
    unsigned short* w1t = xg + (size_t)BATCH * IN_DIM;
    cvt_all_kernel<<<8192, 256, 0, stream>>>(x, (uint4*)xg, W1, (ushort4*)w1t);
    mlp_gemm_kernel<<<(NCOL / 128) * (BATCH / 128), 256, 0, stream>>>(
        w1t, xg, (const f32x4*)b1, (const f32x4*)W2, b2, out);
  } else {
    fallback_kernel<<<(BATCH * OUT_DIM + 255) / 256, 256, 0, stream>>>(x, W1, b1, W2, b2, out);
  }
}